// Round 1
// baseline (456.979 us; speedup 1.0000x reference)
//
#include <hip/hip_runtime.h>
#include <hip/hip_bf16.h>
#include <stdint.h>

// Problem dims (fixed by setup_inputs)
#define T_DIM 2048
#define I_DIM 4096
#define O_DIM 4096
#define R_DIM 16
#define QBLK  32

typedef __bf16 bf16x8 __attribute__((ext_vector_type(8)));
typedef float  floatx4 __attribute__((ext_vector_type(4)));
typedef unsigned short ushort_t;

#define AS1 __attribute__((address_space(1)))
#define AS3 __attribute__((address_space(3)))

__device__ __forceinline__ ushort_t f2bf(float f) {
  unsigned u = __float_as_uint(f);
  u += 0x7FFFu + ((u >> 16) & 1u);   // round-to-nearest-even
  return (ushort_t)(u >> 16);
}

__device__ __forceinline__ float dot4(float4 a, float4 b) {
  return a.x * b.x + a.y * b.y + a.z * b.z + a.w * b.w;
}

// ------------- merged prep: xb=bf16(x) | wb=dequant(q) | xd=alpha*x@down^T
// Block ranges: [0,4096) prep_x, [4096,12288) prep_w, [12288,12544) xd.
__global__ __launch_bounds__(256) void k_prep(const float* __restrict__ x,
                                              const int* __restrict__ q,
                                              const float* __restrict__ scales,
                                              const float* __restrict__ down,
                                              const float* __restrict__ alphap,
                                              ushort_t* __restrict__ xb,
                                              ushort_t* __restrict__ wb,
                                              float* __restrict__ xd) {
  __shared__ float ds[16 * 512];              // 32 KB, used by xd branch only
  const int b = blockIdx.x, tid = threadIdx.x;

  if (b < 4096) {                             // ---- prep_x
    int idx = b * 256 + tid;                  // 8-element chunk id
    const float4* xp = (const float4*)x;
    float4 a = xp[idx * 2], c = xp[idx * 2 + 1];
    union { ushort_t u[8]; uint4 v; } r;
    r.u[0] = f2bf(a.x); r.u[1] = f2bf(a.y); r.u[2] = f2bf(a.z); r.u[3] = f2bf(a.w);
    r.u[4] = f2bf(c.x); r.u[5] = f2bf(c.y); r.u[6] = f2bf(c.z); r.u[7] = f2bf(c.w);
    ((uint4*)xb)[idx] = r.v;
    return;
  }
  if (b < 12288) {                            // ---- prep_w
    int idx = (b - 4096) * 256 + tid;
    int o  = idx >> 9;
    int i0 = (idx & 511) * 8;
    float s = scales[o * (I_DIM / QBLK) + (i0 >> 5)];
    const int4* qp = (const int4*)(q + (size_t)o * I_DIM + i0);
    int4 q0 = qp[0], q1 = qp[1];
    union { ushort_t u[8]; uint4 v; } r;
    r.u[0] = f2bf((float)(q0.x - 8) * s); r.u[1] = f2bf((float)(q0.y - 8) * s);
    r.u[2] = f2bf((float)(q0.z - 8) * s); r.u[3] = f2bf((float)(q0.w - 8) * s);
    r.u[4] = f2bf((float)(q1.x - 8) * s); r.u[5] = f2bf((float)(q1.y - 8) * s);
    r.u[6] = f2bf((float)(q1.z - 8) * s); r.u[7] = f2bf((float)(q1.w - 8) * s);
    ((uint4*)wb)[idx] = r.v;
    return;
  }
  // ---- xd = alpha * (x @ down^T), 8 tokens per block
  {
    const int blk = b - 12288;
    const int tl = tid >> 5, s = tid & 31;
    const int t = blk * 8 + tl;
    float acc[16];
#pragma unroll
    for (int r = 0; r < 16; ++r) acc[r] = 0.f;
    for (int c = 0; c < 8; ++c) {
      const int ib = c * 512;
      __syncthreads();
#pragma unroll
      for (int j = 0; j < 8; ++j) {
        int e = j * 256 + tid;
        int r = e >> 7, col = e & 127;
        ((float4*)ds)[e] = ((const float4*)(down + (size_t)r * I_DIM + ib))[col];
      }
      __syncthreads();
#pragma unroll
      for (int j = 0; j < 4; ++j) {
        float4 xv = ((const float4*)(x + (size_t)t * I_DIM + ib))[s + 32 * j];
#pragma unroll
        for (int r = 0; r < 16; ++r) {
          float4 dv = ((const float4*)ds)[r * 128 + s + 32 * j];
          acc[r] += dot4(xv, dv);
        }
      }
    }
    const float al = alphap[0];
#pragma unroll
    for (int r = 0; r < 16; ++r) {
      float v = acc[r];
      v += __shfl_down(v, 16, 32);
      v += __shfl_down(v, 8, 32);
      v += __shfl_down(v, 4, 32);
      v += __shfl_down(v, 2, 32);
      v += __shfl_down(v, 1, 32);
      if (s == 0) xd[t * 16 + r] = v * al;
    }
  }
}

// ======================= R6 main GEMM ==================================
// y = xb @ wb^T + lora-epilogue + bias.
// Structure change vs R5 (T3+T4+T5 port, cdna guide §5.5):
//  - 128x128 tile, 4 waves (2x2), per-wave 64x64 (acc 4x4 = 64 VGPR).
//    MFMA:ds_read ratio 2.0 vs R5's 1.33 -> LDS pipe no longer 2x
//    oversubscribed.
//  - BK=32, 4-deep LDS ring (4 x 16KB = 64KB static, m132-proven size);
//    2 blocks/CU (128KB LDS/CU).
//  - Counted vmcnt: stage tile kt+3 while computing kt; single
//    s_waitcnt vmcnt(8) per K-tile (T4) with RAW s_barrier (no
//    __syncthreads vmcnt(0) drain). Tail peeled vmcnt(4)/vmcnt(0).
//  - 2 phases per tile: {6 ds_read | stage A} MFMA x8 ; {2 ds_read |
//    stage B} MFMA x8, each wrapped in setprio(1/0) (T5).
//  - XOR granule swizzle carried over (both-sides involution, rule #21):
//    staging writes global granule (seg&3)^(r&3), reads undo it.
//  - XCD-chunked 1-D grid swizzle (512 blocks % 8 == 0, bijective):
//    each XCD owns 4 O-panels x all T-tiles -> B slice 4MB ~= one L2.

#define BK 32
#define NT (I_DIM / BK)        // 128 K-tiles
#define TILE_E (128 * BK)      // 4096 bf16 = 8KB per A/B tile

__device__ __forceinline__ void stage2(const ushort_t* __restrict__ g,
                                       ushort_t* lds0, int wv, int lane) {
  // 128x32 bf16 tile = 512 16B-granules; 256 threads x 2 loads.
  // LDS dest linear (wave-uniform base + lane*16); global src pre-swizzled.
#pragma unroll
  for (int it = 0; it < 2; ++it) {
    const int seg_base = it * 256 + wv * 64;        // wave-uniform
    const int seg = seg_base + lane;
    const int r  = seg >> 2;                        // row [0,128)
    const int cg = (seg & 3) ^ (r & 3);             // swizzled col-granule
    __builtin_amdgcn_global_load_lds(
        (const AS1 char*)(g + (size_t)r * I_DIM + cg * 8),
        (AS3 char*)(lds0 + seg_base * 8), 16, 0, 0);
  }
}

// One K-tile: 2 phases, 16 MFMA. VM: vmcnt immediate at tile end
// (8 steady / 4,0 tail / -1 none). STG: stage tile kt+3.
template<int VM, bool STG>
__device__ __forceinline__ void ktile(const ushort_t* __restrict__ Ac,
                                      const ushort_t* __restrict__ Bc,
                                      ushort_t* Ast, ushort_t* Bst,
                                      const ushort_t* ga, const ushort_t* gb,
                                      floatx4 (&acc)[4][4], int wv, int lane) {
  const int quad = lane >> 4, m16 = lane & 15;
  const int wm = wv >> 1, wn = wv & 1;
  bf16x8 af[4], bf0[2], bf1[2];

  // ---------------- phase 0: read A(all) + B(0,1); stage next-A --------
#pragma unroll
  for (int im = 0; im < 4; ++im) {
    const int m = wm * 64 + im * 16 + m16;
    af[im] = *(const bf16x8*)(Ac + (m * 4 + (quad ^ (m & 3))) * 8);
  }
#pragma unroll
  for (int in_ = 0; in_ < 2; ++in_) {
    const int n = wn * 64 + in_ * 16 + m16;
    bf0[in_] = *(const bf16x8*)(Bc + (n * 4 + (quad ^ (n & 3))) * 8);
  }
  if constexpr (STG) stage2(ga, Ast, wv, lane);
  __builtin_amdgcn_s_barrier();
  asm volatile("s_waitcnt lgkmcnt(0)" ::: "memory");
  __builtin_amdgcn_sched_barrier(0);
  __builtin_amdgcn_s_setprio(1);
#pragma unroll
  for (int im = 0; im < 4; ++im)
#pragma unroll
    for (int in_ = 0; in_ < 2; ++in_)
      acc[im][in_] = __builtin_amdgcn_mfma_f32_16x16x32_bf16(
          af[im], bf0[in_], acc[im][in_], 0, 0, 0);
  __builtin_amdgcn_s_setprio(0);
  __builtin_amdgcn_s_barrier();

  // ---------------- phase 1: read B(2,3); stage next-B -----------------
#pragma unroll
  for (int in_ = 0; in_ < 2; ++in_) {
    const int n = wn * 64 + (in_ + 2) * 16 + m16;
    bf1[in_] = *(const bf16x8*)(Bc + (n * 4 + (quad ^ (n & 3))) * 8);
  }
  if constexpr (STG) stage2(gb, Bst, wv, lane);
  __builtin_amdgcn_s_barrier();
  asm volatile("s_waitcnt lgkmcnt(0)" ::: "memory");
  __builtin_amdgcn_sched_barrier(0);
  __builtin_amdgcn_s_setprio(1);
#pragma unroll
  for (int im = 0; im < 4; ++im)
#pragma unroll
    for (int in_ = 0; in_ < 2; ++in_)
      acc[im][in_ + 2] = __builtin_amdgcn_mfma_f32_16x16x32_bf16(
          af[im], bf1[in_], acc[im][in_ + 2], 0, 0, 0);
  __builtin_amdgcn_s_setprio(0);
  // Tile-end: counted vmcnt BEFORE the barrier -> after the barrier all
  // waves' loads for tile kt+1 have landed (in-order vmcnt retirement).
  if constexpr (VM == 8)      asm volatile("s_waitcnt vmcnt(8)" ::: "memory");
  else if constexpr (VM == 4) asm volatile("s_waitcnt vmcnt(4)" ::: "memory");
  else if constexpr (VM == 0) asm volatile("s_waitcnt vmcnt(0)" ::: "memory");
  if constexpr (VM >= 0) __builtin_amdgcn_sched_barrier(0);
  __builtin_amdgcn_s_barrier();
}

__global__ __launch_bounds__(256, 2) void k_gemm(const ushort_t* __restrict__ xb,
                                                 const ushort_t* __restrict__ wb,
                                                 const float* __restrict__ bias,
                                                 const float* __restrict__ xd,
                                                 const float* __restrict__ up,
                                                 float* __restrict__ y) {
  __shared__ __align__(16) ushort_t As[4][TILE_E];   // 32 KB
  __shared__ __align__(16) ushort_t Bs[4][TILE_E];   // 32 KB

  const int tid = threadIdx.x;
  const int wv = tid >> 6, lane = tid & 63;

  // XCD-chunked swizzle: XCD x owns sid in [64x, 64x+64) = 4 O-panels x 16 T.
  const int id = blockIdx.x;
  const int sid = (id & 7) * 64 + (id >> 3);
  const int bx = sid >> 4;                  // O tile [0,32)
  const int by = sid & 15;                  // T tile [0,16)
  const int oT = bx * 128, tT = by * 128;

  const ushort_t* ap = xb + (size_t)tT * I_DIM;
  const ushort_t* bp = wb + (size_t)oT * I_DIM;

  floatx4 acc[4][4] = {};

  // Prologue: stage tiles 0,1,2 (12 loads/wave); wait tile 0 (vmcnt 8).
#pragma unroll
  for (int t = 0; t < 3; ++t) {
    stage2(ap + t * BK, As[t], wv, lane);
    stage2(bp + t * BK, Bs[t], wv, lane);
  }
  asm volatile("s_waitcnt vmcnt(8)" ::: "memory");
  __builtin_amdgcn_sched_barrier(0);
  __builtin_amdgcn_s_barrier();

  for (int kt = 0; kt < NT - 3; ++kt) {
    const int cur = kt & 3, st = (kt + 3) & 3;
    ktile<8, true>(As[cur], Bs[cur], As[st], Bs[st],
                   ap + (size_t)(kt + 3) * BK, bp + (size_t)(kt + 3) * BK,
                   acc, wv, lane);
  }
  // Tail: tiles NT-3, NT-2, NT-1 (buffers 1,2,3) — no staging.
  ktile<4, false>(As[(NT - 3) & 3], Bs[(NT - 3) & 3], nullptr, nullptr,
                  nullptr, nullptr, acc, wv, lane);
  ktile<0, false>(As[(NT - 2) & 3], Bs[(NT - 2) & 3], nullptr, nullptr,
                  nullptr, nullptr, acc, wv, lane);
  ktile<-1, false>(As[(NT - 1) & 3], Bs[(NT - 1) & 3], nullptr, nullptr,
                   nullptr, nullptr, acc, wv, lane);

  // Epilogue: y[t][o] = acc + dot16(xd[t], up[o]) + bias[o]
  // C/D layout: row = quad*4+reg, col = lane&15 (m89-verified).
  const int quad = lane >> 4, m16 = lane & 15;
  const int wm = wv >> 1, wn = wv & 1;
#pragma unroll
  for (int im = 0; im < 4; ++im) {
#pragma unroll
    for (int reg = 0; reg < 4; ++reg) {
      const int t = tT + wm * 64 + im * 16 + quad * 4 + reg;
      const float4* xr = (const float4*)(xd + t * 16);
      float4 x0 = xr[0], x1 = xr[1], x2 = xr[2], x3 = xr[3];
#pragma unroll
      for (int in_ = 0; in_ < 4; ++in_) {
        const int o = oT + wn * 64 + in_ * 16 + m16;
        const float4* ur = (const float4*)(up + (size_t)o * R_DIM);
        float lv = dot4(x0, ur[0]) + dot4(x1, ur[1]) +
                   dot4(x2, ur[2]) + dot4(x3, ur[3]);
        y[(size_t)t * O_DIM + o] = acc[im][in_][reg] + lv + bias[o];
      }
    }
  }
}

extern "C" void kernel_launch(void* const* d_in, const int* in_sizes, int n_in,
                              void* d_out, int out_size, void* d_ws, size_t ws_size,
                              hipStream_t stream) {
  const float* x      = (const float*)d_in[0];
  const int*   q      = (const int*)d_in[1];
  const float* scales = (const float*)d_in[2];
  const float* up     = (const float*)d_in[3];
  const float* down   = (const float*)d_in[4];
  const float* alpha  = (const float*)d_in[5];
  const float* bias   = (const float*)d_in[6];
  float* y = (float*)d_out;

  // ws layout: xb bf16 [T,I] (16 MB) | wb bf16 [O,I] (32 MB) | xd f32 [T,16]
  ushort_t* xb = (ushort_t*)d_ws;
  ushort_t* wb = (ushort_t*)((char*)d_ws + (size_t)T_DIM * I_DIM * 2);
  float*    xd = (float*)((char*)d_ws + (size_t)T_DIM * I_DIM * 2 + (size_t)O_DIM * I_DIM * 2);

  hipLaunchKernelGGL(k_prep, dim3(4096 + 8192 + 256), dim3(256), 0, stream,
                     x, q, scales, down, alpha, xb, wb, xd);
  hipLaunchKernelGGL(k_gemm, dim3((O_DIM / 128) * (T_DIM / 128)), dim3(256), 0, stream,
                     xb, wb, bias, xd, up, y);
}

// Round 2
// 454.097 us; speedup vs baseline: 1.0063x; 1.0063x over previous
//
#include <hip/hip_runtime.h>
#include <hip/hip_bf16.h>
#include <stdint.h>

// Problem dims (fixed by setup_inputs)
#define T_DIM 2048
#define I_DIM 4096
#define O_DIM 4096
#define R_DIM 16
#define QBLK  32

typedef __bf16 bf16x8 __attribute__((ext_vector_type(8)));
typedef float  floatx4 __attribute__((ext_vector_type(4)));
typedef unsigned short ushort_t;

#define AS1 __attribute__((address_space(1)))
#define AS3 __attribute__((address_space(3)))

__device__ __forceinline__ ushort_t f2bf(float f) {
  unsigned u = __float_as_uint(f);
  u += 0x7FFFu + ((u >> 16) & 1u);   // round-to-nearest-even
  return (ushort_t)(u >> 16);
}

__device__ __forceinline__ float dot4(float4 a, float4 b) {
  return a.x * b.x + a.y * b.y + a.z * b.z + a.w * b.w;
}

// ------------- merged prep: xd | xb=bf16(x) | wb=dequant(q)
// R7: xd blocks moved to the FRONT of the grid (b<256) so their
// latency-bound LDS loop overlaps the 12288 streaming blocks instead of
// running as a serial tail. Block ranges: [0,256) xd, [256,4352) prep_x,
// [4352,12544) prep_w.
__global__ __launch_bounds__(256) void k_prep(const float* __restrict__ x,
                                              const int* __restrict__ q,
                                              const float* __restrict__ scales,
                                              const float* __restrict__ down,
                                              const float* __restrict__ alphap,
                                              ushort_t* __restrict__ xb,
                                              ushort_t* __restrict__ wb,
                                              float* __restrict__ xd) {
  __shared__ float ds[16 * 512];              // 32 KB, used by xd branch only
  const int b = blockIdx.x, tid = threadIdx.x;

  if (b >= 256 && b < 4352) {                 // ---- prep_x
    int idx = (b - 256) * 256 + tid;          // 8-element chunk id
    const float4* xp = (const float4*)x;
    float4 a = xp[idx * 2], c = xp[idx * 2 + 1];
    union { ushort_t u[8]; uint4 v; } r;
    r.u[0] = f2bf(a.x); r.u[1] = f2bf(a.y); r.u[2] = f2bf(a.z); r.u[3] = f2bf(a.w);
    r.u[4] = f2bf(c.x); r.u[5] = f2bf(c.y); r.u[6] = f2bf(c.z); r.u[7] = f2bf(c.w);
    ((uint4*)xb)[idx] = r.v;
    return;
  }
  if (b >= 4352) {                            // ---- prep_w
    int idx = (b - 4352) * 256 + tid;
    int o  = idx >> 9;
    int i0 = (idx & 511) * 8;
    float s = scales[o * (I_DIM / QBLK) + (i0 >> 5)];
    const int4* qp = (const int4*)(q + (size_t)o * I_DIM + i0);
    int4 q0 = qp[0], q1 = qp[1];
    union { ushort_t u[8]; uint4 v; } r;
    r.u[0] = f2bf((float)(q0.x - 8) * s); r.u[1] = f2bf((float)(q0.y - 8) * s);
    r.u[2] = f2bf((float)(q0.z - 8) * s); r.u[3] = f2bf((float)(q0.w - 8) * s);
    r.u[4] = f2bf((float)(q1.x - 8) * s); r.u[5] = f2bf((float)(q1.y - 8) * s);
    r.u[6] = f2bf((float)(q1.z - 8) * s); r.u[7] = f2bf((float)(q1.w - 8) * s);
    ((uint4*)wb)[idx] = r.v;
    return;
  }
  // ---- xd = alpha * (x @ down^T), 8 tokens per block, b in [0,256)
  {
    const int blk = b;
    const int tl = tid >> 5, s = tid & 31;
    const int t = blk * 8 + tl;
    float acc[16];
#pragma unroll
    for (int r = 0; r < 16; ++r) acc[r] = 0.f;
    for (int c = 0; c < 8; ++c) {
      const int ib = c * 512;
      __syncthreads();
#pragma unroll
      for (int j = 0; j < 8; ++j) {
        int e = j * 256 + tid;
        int r = e >> 7, col = e & 127;
        ((float4*)ds)[e] = ((const float4*)(down + (size_t)r * I_DIM + ib))[col];
      }
      __syncthreads();
#pragma unroll
      for (int j = 0; j < 4; ++j) {
        float4 xv = ((const float4*)(x + (size_t)t * I_DIM + ib))[s + 32 * j];
#pragma unroll
        for (int r = 0; r < 16; ++r) {
          float4 dv = ((const float4*)ds)[r * 128 + s + 32 * j];
          acc[r] += dot4(xv, dv);
        }
      }
    }
    const float al = alphap[0];
#pragma unroll
    for (int r = 0; r < 16; ++r) {
      float v = acc[r];
      v += __shfl_down(v, 16, 32);
      v += __shfl_down(v, 8, 32);
      v += __shfl_down(v, 4, 32);
      v += __shfl_down(v, 2, 32);
      v += __shfl_down(v, 1, 32);
      if (s == 0) xd[t * 16 + r] = v * al;
    }
  }
}

// ======================= R7 main GEMM ==================================
// R6 post-mortem: MfmaUtil 9.4% — pipeline drained. Root cause theory:
// C++ ds_reads from LDS cannot be disambiguated from in-flight
// global_load_lds DMA writes, so the compiler inserts s_waitcnt vmcnt(0)
// before them, killing the counted-vmcnt pipeline (rule #18 regime).
// R7 changes:
//  1. Fragment loads are inline-asm ds_read_b128 (opaque to aliasing);
//     explicit lgkmcnt(0)+sched_barrier(0) fence before the MFMAs.
//  2. One phase per K-tile: {8 ds_read | 4 stage} -> barrier ->
//     16 MFMA -> vmcnt(8) -> barrier. Halves barrier count; 16 MFMA per
//     barrier pair (m201 phase size).
//  3. Swizzle f(r) = (r + (r>>2)) & 3 (was r&3): spreads the 16 rows a
//     quarter-wave reads over all 4 granule slots -> 2-way (free) instead
//     of 4-way bank conflict. Applied on BOTH stage-src and read.
// Geometry unchanged: 128x128 tile, 4 waves 2x2, per-wave 64x64, BK=32,
// ring-4 (64KB LDS), 2 blocks/CU, XCD-chunked grid swizzle.

#define BK 32
#define NT (I_DIM / BK)        // 128 K-tiles
#define TILE_E (128 * BK)      // 4096 bf16 = 8KB per A/B tile

__device__ __forceinline__ bf16x8 lds_read16(unsigned addr) {
  bf16x8 d;
  asm volatile("ds_read_b128 %0, %1" : "=v"(d) : "v"(addr));
  return d;
}

__device__ __forceinline__ void stage2(const ushort_t* __restrict__ g,
                                       ushort_t* lds0, int wv, int lane) {
  // 128x32 bf16 tile = 512 16B-granules; 256 threads x 2 loads.
  // LDS dest linear (wave-uniform base + lane*16); global src pre-swizzled
  // with the same involution f(r) the reads use.
#pragma unroll
  for (int it = 0; it < 2; ++it) {
    const int seg_base = it * 256 + wv * 64;        // wave-uniform
    const int seg = seg_base + lane;
    const int r  = seg >> 2;                        // row [0,128)
    const int cg = (seg & 3) ^ ((r + (r >> 2)) & 3);
    __builtin_amdgcn_global_load_lds(
        (const AS1 char*)(g + (size_t)r * I_DIM + cg * 8),
        (AS3 char*)(lds0 + seg_base * 8), 16, 0, 0);
  }
}

// One K-tile, one phase, 16 MFMA. VM: vmcnt immediate at tile end
// (8 steady / 4,0 tail / -1 none). STG: stage tile kt+3.
template<int VM, bool STG>
__device__ __forceinline__ void ktile(unsigned aB, unsigned bB,
                                      ushort_t* Ast, ushort_t* Bst,
                                      const ushort_t* ga, const ushort_t* gb,
                                      floatx4 (&acc)[4][4], int wv, int lane) {
  const int quad = lane >> 4, m16 = lane & 15;
  const int wm = wv >> 1, wn = wv & 1;
  bf16x8 af[4], bfr[4];
#pragma unroll
  for (int im = 0; im < 4; ++im) {
    const int m = wm * 64 + im * 16 + m16;
    af[im] = lds_read16(aB + (unsigned)(m * 64 + ((quad ^ ((m + (m >> 2)) & 3)) << 4)));
  }
#pragma unroll
  for (int in_ = 0; in_ < 4; ++in_) {
    const int n = wn * 64 + in_ * 16 + m16;
    bfr[in_] = lds_read16(bB + (unsigned)(n * 64 + ((quad ^ ((n + (n >> 2)) & 3)) << 4)));
  }
  if constexpr (STG) { stage2(ga, Ast, wv, lane); stage2(gb, Bst, wv, lane); }
  __builtin_amdgcn_s_barrier();
  asm volatile("s_waitcnt lgkmcnt(0)" ::: "memory");
  __builtin_amdgcn_sched_barrier(0);              // rule #18: pin MFMAs below
  __builtin_amdgcn_s_setprio(1);
#pragma unroll
  for (int im = 0; im < 4; ++im)
#pragma unroll
    for (int in_ = 0; in_ < 4; ++in_)
      acc[im][in_] = __builtin_amdgcn_mfma_f32_16x16x32_bf16(
          af[im], bfr[in_], acc[im][in_], 0, 0, 0);
  __builtin_amdgcn_s_setprio(0);
  // Tile-end: counted vmcnt BEFORE the barrier -> after the barrier all
  // waves' loads for tile kt+1 have landed (in-order vmcnt retirement).
  if constexpr (VM == 8)      asm volatile("s_waitcnt vmcnt(8)" ::: "memory");
  else if constexpr (VM == 4) asm volatile("s_waitcnt vmcnt(4)" ::: "memory");
  else if constexpr (VM == 0) asm volatile("s_waitcnt vmcnt(0)" ::: "memory");
  if constexpr (VM >= 0) __builtin_amdgcn_sched_barrier(0);
  __builtin_amdgcn_s_barrier();
}

__global__ __launch_bounds__(256, 2) void k_gemm(const ushort_t* __restrict__ xb,
                                                 const ushort_t* __restrict__ wb,
                                                 const float* __restrict__ bias,
                                                 const float* __restrict__ xd,
                                                 const float* __restrict__ up,
                                                 float* __restrict__ y) {
  __shared__ __align__(16) ushort_t As[4][TILE_E];   // 32 KB
  __shared__ __align__(16) ushort_t Bs[4][TILE_E];   // 32 KB

  const int tid = threadIdx.x;
  const int wv = tid >> 6, lane = tid & 63;

  // XCD-chunked swizzle: XCD x owns sid in [64x, 64x+64) = 4 O-panels x 16 T.
  const int id = blockIdx.x;
  const int sid = (id & 7) * 64 + (id >> 3);
  const int bx = sid >> 4;                  // O tile [0,32)
  const int by = sid & 15;                  // T tile [0,16)
  const int oT = bx * 128, tT = by * 128;

  const ushort_t* ap = xb + (size_t)tT * I_DIM;
  const ushort_t* bp = wb + (size_t)oT * I_DIM;

  // LDS byte offsets (AS3 pointer -> 32-bit LDS address) for asm reads.
  const unsigned asB = (unsigned)(uintptr_t)(AS3 ushort_t*)&As[0][0];
  const unsigned bsB = (unsigned)(uintptr_t)(AS3 ushort_t*)&Bs[0][0];

  floatx4 acc[4][4] = {};

  // Prologue: stage tiles 0,1,2 (12 loads/wave); wait tile 0 (vmcnt 8).
#pragma unroll
  for (int t = 0; t < 3; ++t) {
    stage2(ap + t * BK, As[t], wv, lane);
    stage2(bp + t * BK, Bs[t], wv, lane);
  }
  asm volatile("s_waitcnt vmcnt(8)" ::: "memory");
  __builtin_amdgcn_sched_barrier(0);
  __builtin_amdgcn_s_barrier();

  for (int kt = 0; kt < NT - 3; ++kt) {
    const int cur = kt & 3, st = (kt + 3) & 3;
    ktile<8, true>(asB + cur * (TILE_E * 2), bsB + cur * (TILE_E * 2),
                   As[st], Bs[st],
                   ap + (size_t)(kt + 3) * BK, bp + (size_t)(kt + 3) * BK,
                   acc, wv, lane);
  }
  // Tail: tiles NT-3, NT-2, NT-1 — no staging, drain vmcnt 4 -> 0.
  ktile<4, false>(asB + ((NT - 3) & 3) * (TILE_E * 2), bsB + ((NT - 3) & 3) * (TILE_E * 2),
                  nullptr, nullptr, nullptr, nullptr, acc, wv, lane);
  ktile<0, false>(asB + ((NT - 2) & 3) * (TILE_E * 2), bsB + ((NT - 2) & 3) * (TILE_E * 2),
                  nullptr, nullptr, nullptr, nullptr, acc, wv, lane);
  ktile<-1, false>(asB + ((NT - 1) & 3) * (TILE_E * 2), bsB + ((NT - 1) & 3) * (TILE_E * 2),
                   nullptr, nullptr, nullptr, nullptr, acc, wv, lane);

  // Epilogue: y[t][o] = acc + dot16(xd[t], up[o]) + bias[o]
  // C/D layout: row = quad*4+reg, col = lane&15 (m89-verified).
  const int quad = lane >> 4, m16 = lane & 15;
  const int wm = wv >> 1, wn = wv & 1;
#pragma unroll
  for (int im = 0; im < 4; ++im) {
#pragma unroll
    for (int reg = 0; reg < 4; ++reg) {
      const int t = tT + wm * 64 + im * 16 + quad * 4 + reg;
      const float4* xr = (const float4*)(xd + t * 16);
      float4 x0 = xr[0], x1 = xr[1], x2 = xr[2], x3 = xr[3];
#pragma unroll
      for (int in_ = 0; in_ < 4; ++in_) {
        const int o = oT + wn * 64 + in_ * 16 + m16;
        const float4* ur = (const float4*)(up + (size_t)o * R_DIM);
        float lv = dot4(x0, ur[0]) + dot4(x1, ur[1]) +
                   dot4(x2, ur[2]) + dot4(x3, ur[3]);
        y[(size_t)t * O_DIM + o] = acc[im][in_][reg] + lv + bias[o];
      }
    }
  }
}

extern "C" void kernel_launch(void* const* d_in, const int* in_sizes, int n_in,
                              void* d_out, int out_size, void* d_ws, size_t ws_size,
                              hipStream_t stream) {
  const float* x      = (const float*)d_in[0];
  const int*   q      = (const int*)d_in[1];
  const float* scales = (const float*)d_in[2];
  const float* up     = (const float*)d_in[3];
  const float* down   = (const float*)d_in[4];
  const float* alpha  = (const float*)d_in[5];
  const float* bias   = (const float*)d_in[6];
  float* y = (float*)d_out;

  // ws layout: xb bf16 [T,I] (16 MB) | wb bf16 [O,I] (32 MB) | xd f32 [T,16]
  ushort_t* xb = (ushort_t*)d_ws;
  ushort_t* wb = (ushort_t*)((char*)d_ws + (size_t)T_DIM * I_DIM * 2);
  float*    xd = (float*)((char*)d_ws + (size_t)T_DIM * I_DIM * 2 + (size_t)O_DIM * I_DIM * 2);

  hipLaunchKernelGGL(k_prep, dim3(256 + 4096 + 8192), dim3(256), 0, stream,
                     x, q, scales, down, alpha, xb, wb, xd);
  hipLaunchKernelGGL(k_gemm, dim3((O_DIM / 128) * (T_DIM / 128)), dim3(256), 0, stream,
                     xb, wb, bias, xd, up, y);
}